// Round 6
// baseline (665.590 us; speedup 1.0000x reference)
//
#include <hip/hip_runtime.h>
#include <stdint.h>
#include <stddef.h>

#define B_ 1024
#define S_ 512
#define I_ 64
#define H_ 128
#define G_ 512       // 4H
#define KTOT 192     // I + H
#define ROWS 4       // batch rows per block (256 blocks -> all 256 CUs)
#define RSTRIDE 288  // h row stride bytes: 256 data + 32 pad (72 dw == 8 mod 32 -> 2-way banks)
#define HBUF (ROWS * RSTRIDE)     // 1152 B per h buffer
#define XRSTRIDE 160              // xr row stride bytes: 128 data + 32 pad
#define XRBUF (ROWS * XRSTRIDE)   // 640 B per xr buffer

typedef __bf16 bf16;
typedef __bf16 bf16x8 __attribute__((ext_vector_type(8)));
typedef float f32x4 __attribute__((ext_vector_type(4)));
typedef unsigned short u16;
typedef unsigned short u16x4 __attribute__((ext_vector_type(4)));

// ---- workspace layout (bytes) ---- total ~207 KB
#define WS_WCT  ((size_t)0)                      // bf16 [G][KTOT]
#define WS_BIAS (WS_WCT + (size_t)G_*KTOT*2)     // f32  [G]
#define WS_M16  (WS_BIAS + (size_t)G_*4)         // bf16 [I][I] (collapsed FFN)
#define WS_CVEC (WS_M16 + (size_t)I_*I_*2)       // f32  [I]

// ---------------------------------------------------------------------------
// Precompute: M16 = bf16(W1*W0) (FFN collapse), cvec = b1 + W1*b0,
// biascat = b_ih+b_hh, wct[n][k] = concat(W_ih, W_hh) rows as bf16.
// ---------------------------------------------------------------------------
__global__ __launch_bounds__(256) void precompute_kernel(
    const float* __restrict__ W0, const float* __restrict__ b0,
    const float* __restrict__ W1, const float* __restrict__ b1,
    const float* __restrict__ W_ih, const float* __restrict__ W_hh,
    const float* __restrict__ b_ih, const float* __restrict__ b_hh,
    char* __restrict__ ws)
{
  int tid = blockIdx.x * 256 + threadIdx.x;   // grid 64x256 = 16384 threads
  bf16*  m16     = (bf16*)(ws + WS_M16);
  float* cvec    = (float*)(ws + WS_CVEC);
  float* biascat = (float*)(ws + WS_BIAS);
  bf16*  wct     = (bf16*)(ws + WS_WCT);

  if (tid < 4096) {
    int i = tid >> 6, k = tid & 63;
    float acc = 0.f;
    for (int j = 0; j < 256; ++j) acc += W1[i*256 + j] * W0[j*64 + k];
    m16[tid] = (bf16)acc;
  } else if (tid < 4160) {
    int i = tid - 4096;
    float acc = b1[i];
    for (int j = 0; j < 256; ++j) acc += W1[i*256 + j] * b0[j];
    cvec[i] = acc;
  } else if (tid < 4672) {
    int n = tid - 4160;
    biascat[n] = b_ih[n] + b_hh[n];
  }
  for (int e = tid; e < G_*KTOT; e += 16384) {
    int n = e / KTOT, k = e % KTOT;
    float v = (k < I_) ? W_ih[n*I_ + k] : W_hh[n*H_ + (k - I_)];
    wct[e] = (bf16)v;
  }
}

// ---------------------------------------------------------------------------
// Fully fused FFN + LSTM scan + final projection.
// 256 blocks x 512 threads (8 waves); block owns batch rows [4*blk, +4).
// MFMA-pipe-bound design notes (from r5 counters):
//  * 200 MFMAs/CU-step = 50/SIMD x 19.4cy = 970cy floor -> everything else
//    must hide under it.
//  * A-frag rows are batch-clamped (ar=lr&3), so C rows 4..15 are BIT-EXACT
//    replicas of rows 0..3 -> every lane holds all 4 batches' gate values;
//    3 v_cndmask select acc[q][lg] (no LDS stage, no bpermute).
//  * Raw s_barrier + lgkmcnt(0)-only drain: x prefetch (2-step-deep, two
//    register sets, 2x-unrolled loop) stays in flight across barriers
//    (T3/T4 counted-wait pattern; __syncthreads would vmcnt(0)-drain it).
//  * h/xr ping-pong in pad-288/160B LDS rows (2-way banks = free); all DS
//    addressing via per-lane bases + compile-time offset: immediates.
// ---------------------------------------------------------------------------
__device__ inline float sigmf(float x) {
  float e = __builtin_amdgcn_exp2f(-1.4426950408889634f * x);
  return __builtin_amdgcn_rcpf(1.f + e);
}
__device__ inline float tanhf_(float x) {            // 2*sigma(2x) - 1
  float e = __builtin_amdgcn_exp2f(-2.8853900817779268f * x);
  float r = __builtin_amdgcn_rcpf(1.f + e);
  return 2.f * r - 1.f;                              // x->-inf: rcp(inf)=0 -> -1
}

// select element lg (0..3) of a f32x4 with static indices (rule-#20-safe)
#define SELQ(A) ((lg & 2) ? ((lg & 1) ? (A)[3] : (A)[2]) \
                          : ((lg & 1) ? (A)[1] : (A)[0]))

#define LSTM_STEP(P, XQ0, XQ1, XQ2, XQ3, XRES, SN)                            \
  {                                                                           \
    /* A-frags from LDS slot P (immediate offsets off per-lane bases) */      \
    bf16x8 axr0 = *(const bf16x8*)(xr_rd + (P)*XRBUF);                        \
    bf16x8 axr1 = *(const bf16x8*)(xr_rd + (P)*XRBUF + 64);                   \
    bf16x8 ah0  = *(const bf16x8*)(h_rd + (P)*HBUF);                          \
    bf16x8 ah1  = *(const bf16x8*)(h_rd + (P)*HBUF + 64);                     \
    bf16x8 ah2  = *(const bf16x8*)(h_rd + (P)*HBUF + 128);                    \
    bf16x8 ah3  = *(const bf16x8*)(h_rd + (P)*HBUF + 192);                    \
    /* FFN for xr(s+1): register-only MFMAs, waves 0..3 (issue early) */      \
    f32x4 fa = {0.f, 0.f, 0.f, 0.f};                                          \
    if (w < 4) {                                                              \
      bf16x8 xf0, xf1;                                                        \
      _Pragma("unroll")                                                       \
      for (int j = 0; j < 4; ++j) {                                           \
        xf0[j] = (bf16)XQ0[j]; xf0[4+j] = (bf16)XQ1[j];                       \
        xf1[j] = (bf16)XQ2[j]; xf1[4+j] = (bf16)XQ3[j];                       \
      }                                                                       \
      fa = __builtin_amdgcn_mfma_f32_16x16x32_bf16(mfrag0, xf0, fa, 0,0,0);   \
      fa = __builtin_amdgcn_mfma_f32_16x16x32_bf16(mfrag1, xf1, fa, 0,0,0);   \
    }                                                                         \
    /* gate MFMAs: 24/wave, 4 independent q-chains of depth 6 */              \
    f32x4 acc[4];                                                             \
    _Pragma("unroll")                                                         \
    for (int q = 0; q < 4; ++q) {                                             \
      acc[q] = (f32x4){0.f, 0.f, 0.f, 0.f};                                   \
      acc[q] = __builtin_amdgcn_mfma_f32_16x16x32_bf16(axr0, wfrag[q][0], acc[q], 0,0,0); \
      acc[q] = __builtin_amdgcn_mfma_f32_16x16x32_bf16(axr1, wfrag[q][1], acc[q], 0,0,0); \
      acc[q] = __builtin_amdgcn_mfma_f32_16x16x32_bf16(ah0,  wfrag[q][2], acc[q], 0,0,0); \
      acc[q] = __builtin_amdgcn_mfma_f32_16x16x32_bf16(ah1,  wfrag[q][3], acc[q], 0,0,0); \
      acc[q] = __builtin_amdgcn_mfma_f32_16x16x32_bf16(ah2,  wfrag[q][4], acc[q], 0,0,0); \
      acc[q] = __builtin_amdgcn_mfma_f32_16x16x32_bf16(ah3,  wfrag[q][5], acc[q], 0,0,0); \
    }                                                                         \
    /* per-lane select (C rows are 4x-replicated): batch=lg, col=w*16+lr */   \
    float ii = sigmf(SELQ(acc[0]) + bias[0]);                                 \
    float ff = sigmf(SELQ(acc[1]) + bias[1]);                                 \
    float gg = tanhf_(SELQ(acc[2]) + bias[2]);                                \
    float oo = sigmf(SELQ(acc[3]) + bias[3]);                                 \
    float cn = ff * c1 + ii * gg;                                             \
    c1 = cn;                                                                  \
    float hn = oo * tanhf_(cn);                                               \
    *(bf16*)(h_wr + ((P)^1)*HBUF) = (bf16)hn;                                 \
    if (w < 4) {                                                              \
      if (lr < ROWS) {   /* xr(s+1) pack: valid batch cols only */            \
        u16x4 pk;                                                             \
        _Pragma("unroll")                                                     \
        for (int r = 0; r < 4; ++r) {                                         \
          float t = fa[r] + cvec4[r] + XRES[r];                               \
          t = t > 0.f ? t : 0.f;                                              \
          pk[r] = __builtin_bit_cast(u16, (bf16)t);                           \
        }                                                                     \
        *(u16x4*)(xr_wr + ((P)^1)*XRBUF) = pk;                                \
      }                                                                       \
      /* prefetch x(SN) into this step's (just-consumed) register set */      \
      const float* bx = x + xrow + (size_t)(SN) * I_;                         \
      XQ0 = *(const f32x4*)(bx + lg*8);                                       \
      XQ1 = *(const f32x4*)(bx + lg*8 + 4);                                   \
      XQ2 = *(const f32x4*)(bx + 32 + lg*8);                                  \
      XQ3 = *(const f32x4*)(bx + 32 + lg*8 + 4);                              \
      XRES = *(const f32x4*)(bx + w*16 + lg*4);                               \
    }                                                                         \
    /* raw barrier: drain LDS only; globals stay in flight (T4) */            \
    __builtin_amdgcn_sched_barrier(0);                                        \
    asm volatile("s_waitcnt lgkmcnt(0)" ::: "memory");                        \
    __builtin_amdgcn_s_barrier();                                             \
    __builtin_amdgcn_sched_barrier(0);                                        \
  }

__global__ __launch_bounds__(512, 2) void scan_kernel(
    const char* __restrict__ ws, const float* __restrict__ x,
    const float* __restrict__ Wf, const float* __restrict__ bfp,
    float* __restrict__ out)
{
  const bf16*  __restrict__ wct     = (const bf16*)(ws + WS_WCT);
  const float* __restrict__ biascat = (const float*)(ws + WS_BIAS);
  const bf16*  __restrict__ m16     = (const bf16*)(ws + WS_M16);
  const float* __restrict__ cvec    = (const float*)(ws + WS_CVEC);

  __shared__ __align__(16) char h_lds[2 * HBUF];     // ping-pong h (bf16)
  __shared__ __align__(16) char xr_lds[2 * XRBUF];   // ping-pong xr (bf16)

  const int tid = threadIdx.x;
  const int w  = tid >> 6;          // wave 0..7
  const int l  = tid & 63;
  const int lr = l & 15;
  const int lg = l >> 4;
  const int ar = lr & (ROWS - 1);   // clamped batch row (-> C-row replication)
  const int b0 = blockIdx.x * ROWS;

  // per-lane LDS base pointers; in-loop DS ops use offset: immediates
  char* xr_rd = xr_lds + ar*XRSTRIDE + lg*16;
  char* h_rd  = h_lds  + ar*RSTRIDE  + lg*16;
  char* h_wr  = h_lds  + lg*RSTRIDE  + (w*16 + lr)*2;
  char* xr_wr = xr_lds + lr*XRSTRIDE + (w*16 + lg*4)*2;

  // ---- resident fragments ----
  bf16x8 wfrag[4][6];               // gate weights: wave w, gate q, k-chunk
  #pragma unroll
  for (int q = 0; q < 4; ++q) {
    int n = q*128 + w*16 + lr;
    #pragma unroll
    for (int kc = 0; kc < 6; ++kc)
      wfrag[q][kc] = *reinterpret_cast<const bf16x8*>(wct + n*KTOT + kc*32 + lg*8);
  }
  float bias[4];
  #pragma unroll
  for (int q = 0; q < 4; ++q) bias[q] = biascat[q*128 + w*16 + lr];

  bf16x8 mfrag0 = *reinterpret_cast<const bf16x8*>(m16 + ((w&3)*16 + lr)*64 + lg*8);
  bf16x8 mfrag1 = *reinterpret_cast<const bf16x8*>(m16 + ((w&3)*16 + lr)*64 + 32 + lg*8);
  f32x4 cvec4 = *reinterpret_cast<const f32x4*>(cvec + (w&3)*16 + lg*4);

  // zero h(0) slot 0
  for (int t = tid; t < HBUF/4; t += 512) reinterpret_cast<int*>(h_lds)[t] = 0;

  // ---- prologue: FFN(0) -> xr slot 0; preload x(1)/x(2) reg sets ----
  const size_t xrow = (size_t)(b0 + ar) * S_ * I_;   // x[b][s][i] row base
  f32x4 aq0={0,0,0,0}, aq1={0,0,0,0}, aq2={0,0,0,0}, aq3={0,0,0,0}, ares={0,0,0,0};
  f32x4 bq0={0,0,0,0}, bq1={0,0,0,0}, bq2={0,0,0,0}, bq3={0,0,0,0}, bres={0,0,0,0};
  if (w < 4) {
    const float* bx = x + xrow;                      // s = 0
    f32x4 q0 = *(const f32x4*)(bx + lg*8);
    f32x4 q1 = *(const f32x4*)(bx + lg*8 + 4);
    f32x4 q2 = *(const f32x4*)(bx + 32 + lg*8);
    f32x4 q3 = *(const f32x4*)(bx + 32 + lg*8 + 4);
    f32x4 rs = *(const f32x4*)(bx + w*16 + lg*4);
    bf16x8 xf0, xf1;
    #pragma unroll
    for (int j = 0; j < 4; ++j) {
      xf0[j] = (bf16)q0[j]; xf0[4+j] = (bf16)q1[j];
      xf1[j] = (bf16)q2[j]; xf1[4+j] = (bf16)q3[j];
    }
    f32x4 fa = {0.f, 0.f, 0.f, 0.f};
    fa = __builtin_amdgcn_mfma_f32_16x16x32_bf16(mfrag0, xf0, fa, 0, 0, 0);
    fa = __builtin_amdgcn_mfma_f32_16x16x32_bf16(mfrag1, xf1, fa, 0, 0, 0);
    if (lr < ROWS) {
      u16x4 pk;
      #pragma unroll
      for (int r = 0; r < 4; ++r) {
        float t = fa[r] + cvec4[r] + rs[r];
        t = t > 0.f ? t : 0.f;
        pk[r] = __builtin_bit_cast(u16, (bf16)t);
      }
      *(u16x4*)(xr_wr) = pk;                         // slot 0
    }
    const float* bx1 = x + xrow + I_;                // x(1) -> set A
    aq0 = *(const f32x4*)(bx1 + lg*8);
    aq1 = *(const f32x4*)(bx1 + lg*8 + 4);
    aq2 = *(const f32x4*)(bx1 + 32 + lg*8);
    aq3 = *(const f32x4*)(bx1 + 32 + lg*8 + 4);
    ares = *(const f32x4*)(bx1 + w*16 + lg*4);
    const float* bx2 = x + xrow + 2*I_;              // x(2) -> set B
    bq0 = *(const f32x4*)(bx2 + lg*8);
    bq1 = *(const f32x4*)(bx2 + lg*8 + 4);
    bq2 = *(const f32x4*)(bx2 + 32 + lg*8);
    bq3 = *(const f32x4*)(bx2 + 32 + lg*8 + 4);
    bres = *(const f32x4*)(bx2 + w*16 + lg*4);
  }

  float c1 = 0.f;                  // cell state: lane owns (hcol=w*16+lr, b=lg)
  __syncthreads();

  // ---- main loop: 2x unrolled, compile-time ping-pong ----
  for (int it = 0; it < S_/2; ++it) {
    int s0 = 2*it;
    int sn3 = (s0 + 3 < S_) ? s0 + 3 : S_ - 1;
    int sn4 = (s0 + 4 < S_) ? s0 + 4 : S_ - 1;
    LSTM_STEP(0, aq0, aq1, aq2, aq3, ares, sn3)
    LSTM_STEP(1, bq0, bq1, bq2, bq3, bres, sn4)
  }

  // ---- final projection: out[b0+row] = h_T[row] . Wf + bf ----
  // step 511 wrote slot 0; last barrier made it visible.
  if (tid < 64) {
    int row = lg, cl = lr * 8;
    bf16x8 hv = *reinterpret_cast<const bf16x8*>(h_lds + row*RSTRIDE + cl*2);
    float accf = 0.f;
    #pragma unroll
    for (int j = 0; j < 8; ++j) accf += (float)hv[j] * Wf[cl + j];
    accf += __shfl_xor(accf, 1, 64);
    accf += __shfl_xor(accf, 2, 64);
    accf += __shfl_xor(accf, 4, 64);
    accf += __shfl_xor(accf, 8, 64);
    if (lr == 0) out[b0 + row] = accf + bfp[0];
  }
}

// ---------------------------------------------------------------------------
extern "C" void kernel_launch(void* const* d_in, const int* in_sizes, int n_in,
                              void* d_out, int out_size, void* d_ws, size_t ws_size,
                              hipStream_t stream)
{
  const float* x    = (const float*)d_in[0];
  const float* W0   = (const float*)d_in[1];
  const float* b0   = (const float*)d_in[2];
  const float* W1   = (const float*)d_in[3];
  const float* b1   = (const float*)d_in[4];
  const float* W_ih = (const float*)d_in[5];
  const float* W_hh = (const float*)d_in[6];
  const float* b_ih = (const float*)d_in[7];
  const float* b_hh = (const float*)d_in[8];
  const float* Wf   = (const float*)d_in[9];
  const float* bf   = (const float*)d_in[10];
  char* ws = (char*)d_ws;
  float* out = (float*)d_out;

  hipLaunchKernelGGL(precompute_kernel, dim3(64), dim3(256), 0, stream,
                     W0, b0, W1, b1, W_ih, W_hh, b_ih, b_hh, ws);
  hipLaunchKernelGGL(scan_kernel, dim3(256), dim3(512), 0, stream,
                     ws, x, Wf, bf, out);
}